// Round 7
// baseline (291.730 us; speedup 1.0000x reference)
//
#include <hip/hip_runtime.h>
#include <hip/hip_bf16.h>
#include <cstdint>
#include <cstddef>

#define N_NODES 100000
#define N_EDGES 1600000
#define F_IN 256
#define F_OUT 128

#define NB 1563       // buckets = row >> 6 (64 rows each); 99999>>6 = 1562
#define NBLK 196      // tiles for the scatter half of fused_mid
#define TILE 8192     // edges per tile
#define CAP 1536      // fixed metabuf slots per bucket (mean 1024, +16 sigma)
#define GEMM_BLOCKS 391

typedef __attribute__((ext_vector_type(8))) short short8;
typedef __attribute__((ext_vector_type(4))) float floatx4;

static __device__ __forceinline__ unsigned short f2bf(float f) {
    union { float f; unsigned u; } v; v.f = f;
    unsigned r = v.u + 0x7FFF + ((v.u >> 16) & 1);   // RNE
    return (unsigned short)(r >> 16);
}

// ---- w prep + cnt zero: fp32 [256][128] -> bf16 swizzled wT ----------------
__global__ void prep_w(const float* __restrict__ w, unsigned short* __restrict__ wT,
                       int* __restrict__ cnt) {
    int i = blockIdx.x * 256 + threadIdx.x;   // 0..32767
    int k = i >> 7;
    int n = i & 127;
    int g = (k >> 3) ^ (n & 7);
    wT[n * 256 + g * 8 + (k & 7)] = f2bf(w[i]);
    if (blockIdx.x == 0)
        for (int j = threadIdx.x; j < NB; j += 256) cnt[j] = 0;
}

// ---- fused_mid: blocks [0,391) = GEMM, [391,587) = bucket scatter ----------
// LDS is 32 KB (round-6 lesson: the 64 KB w-stage capped the whole fused
// kernel at 2 blocks/CU -> 15% occupancy, everything latency-bound).
// GEMM stages w in two K-halves: for k>>3 = 16h+m the swizzled group index
// g = 16h + (m^(n&7)), so half h is a self-contained 32 KB block addressed
// wlds[n*128 + gl*8 + (k&7)], gl=(ksl*4+quad)^(n&7). acc persists across
// halves; 2 extra barriers, no extra global traffic, no VGPR change.
__global__ __launch_bounds__(256, 2) void fused_mid(const float* __restrict__ x,
                                                    const unsigned short* __restrict__ wT,
                                                    unsigned short* __restrict__ h,
                                                    const int* __restrict__ row,
                                                    const int* __restrict__ col,
                                                    const float* __restrict__ val,
                                                    int* __restrict__ cnt,
                                                    int2* __restrict__ metabuf) {
    __shared__ __align__(16) unsigned short smem[128 * 128];   // 32 KB union
    const int tid = threadIdx.x;

    if (blockIdx.x < GEMM_BLOCKS) {
        unsigned short* wlds = smem;
        const int wave = tid >> 6, lane = tid & 63;
        const int quad = lane >> 4, l16 = lane & 15;
        const int rowbase = blockIdx.x * 256 + wave * 64;

        floatx4 acc[4][8];
        #pragma unroll
        for (int mf = 0; mf < 4; mf++)
            #pragma unroll
            for (int nt = 0; nt < 8; nt++) acc[mf][nt] = (floatx4)0.f;

        #pragma unroll
        for (int half = 0; half < 2; half++) {
            if (half) __syncthreads();             // previous compute done
            {   // stage 32 KB: fx4 j=(n,gl) <- wT fx4 [n*32 + 16*half + gl]
                const floatx4* src = reinterpret_cast<const floatx4*>(wT);
                floatx4* dst = reinterpret_cast<floatx4*>(wlds);
                #pragma unroll
                for (int it = 0; it < 8; it++) {
                    int j = tid + it * 256;        // 0..2047
                    int n = j >> 4, gl = j & 15;
                    dst[j] = src[n * 32 + half * 16 + gl];
                }
            }
            __syncthreads();

            #pragma unroll
            for (int ksl = 0; ksl < 4; ksl++) {
                const int ks = half * 4 + ksl;
                const int k0 = ks * 32 + quad * 8;
                short8 afrag[4];
                #pragma unroll
                for (int mf = 0; mf < 4; mf++) {
                    int r = rowbase + mf * 16 + l16;
                    if (r >= N_NODES) r = N_NODES - 1;
                    const float* xp = x + (size_t)r * F_IN + k0;
                    floatx4 x0 = *reinterpret_cast<const floatx4*>(xp);
                    floatx4 x1 = *reinterpret_cast<const floatx4*>(xp + 4);
                    short8 a;
                    a[0] = (short)f2bf(x0[0]); a[1] = (short)f2bf(x0[1]);
                    a[2] = (short)f2bf(x0[2]); a[3] = (short)f2bf(x0[3]);
                    a[4] = (short)f2bf(x1[0]); a[5] = (short)f2bf(x1[1]);
                    a[6] = (short)f2bf(x1[2]); a[7] = (short)f2bf(x1[3]);
                    afrag[mf] = a;
                }
                short8 bfrag[8];
                const int gql = ksl * 4 + quad;
                #pragma unroll
                for (int nt = 0; nt < 8; nt++) {
                    const int n = nt * 16 + l16;
                    const int gl = gql ^ (n & 7);
                    bfrag[nt] = *reinterpret_cast<const short8*>(&wlds[n * 128 + gl * 8]);
                }
                #pragma unroll
                for (int mf = 0; mf < 4; mf++)
                    #pragma unroll
                    for (int nt = 0; nt < 8; nt++)
                        acc[mf][nt] = __builtin_amdgcn_mfma_f32_16x16x32_bf16(
                            afrag[mf], bfrag[nt], acc[mf][nt], 0, 0, 0);
            }
        }

        #pragma unroll
        for (int mf = 0; mf < 4; mf++) {
            const int mbase = rowbase + mf * 16 + quad * 4;
            #pragma unroll
            for (int reg = 0; reg < 4; reg++) {
                const int m = mbase + reg;
                if (m < N_NODES) {
                    short8 hv;
                    #pragma unroll
                    for (int nt = 0; nt < 8; nt++) hv[nt] = (short)f2bf(acc[mf][nt][reg]);
                    *reinterpret_cast<short8*>(&h[(size_t)m * F_OUT + l16 * 8]) = hv;
                }
            }
        }
    } else {
        // ---- scatter half (needs 2*NB*4 = 12.5 KB of smem) ----
        int* hist   = reinterpret_cast<int*>(smem);        // NB ints
        int* cursor = hist + NB;                           // NB ints
        const int blk = blockIdx.x - GEMM_BLOCKS;
        for (int i = tid; i < NB; i += 256) hist[i] = 0;
        __syncthreads();
        const long tb = (long)blk * TILE;
        // pass 1: histogram over row
        #pragma unroll
        for (int c = 0; c < 8; c++) {
            long i0 = tb + c * 1024 + tid * 4;
            if (i0 + 4 <= N_EDGES) {
                int4 r = *reinterpret_cast<const int4*>(row + i0);
                atomicAdd(&hist[r.x >> 6], 1); atomicAdd(&hist[r.y >> 6], 1);
                atomicAdd(&hist[r.z >> 6], 1); atomicAdd(&hist[r.w >> 6], 1);
            } else {
                for (long i = i0; i < N_EDGES && i < i0 + 4; i++)
                    atomicAdd(&hist[row[i] >> 6], 1);
            }
        }
        __syncthreads();
        // reserve global ranges (one atomic per touched bin)
        for (int bin = tid; bin < NB; bin += 256) {
            int hc = hist[bin];
            int base = bin * CAP;
            if (hc) base += atomicAdd(&cnt[bin], hc);
            cursor[bin] = base;
        }
        __syncthreads();
        // pass 2: write edges (row re-read is L2-hot)
        #pragma unroll
        for (int c = 0; c < 8; c++) {
            long i0 = tb + c * 1024 + tid * 4;
            if (i0 + 4 <= N_EDGES) {
                int4 r  = *reinterpret_cast<const int4*>(row + i0);
                int4 cc = *reinterpret_cast<const int4*>(col + i0);
                floatx4 vv = *reinterpret_cast<const floatx4*>(val + i0);
                int rr[4] = {r.x, r.y, r.z, r.w};
                int c4[4] = {cc.x, cc.y, cc.z, cc.w};
                float v4[4] = {vv[0], vv[1], vv[2], vv[3]};
                #pragma unroll
                for (int j = 0; j < 4; j++) {
                    int bin = rr[j] >> 6, rl = rr[j] & 63;
                    int pos = atomicAdd(&cursor[bin], 1);
                    if (pos < (bin + 1) * CAP)
                        metabuf[pos] = make_int2(c4[j] | (rl << 24), __float_as_int(v4[j]));
                }
            } else {
                for (long i = i0; i < N_EDGES && i < i0 + 4; i++) {
                    int rv = row[i];
                    int bin = rv >> 6, rl = rv & 63;
                    int pos = atomicAdd(&cursor[bin], 1);
                    if (pos < (bin + 1) * CAP)
                        metabuf[pos] = make_int2(col[i] | (rl << 24), __float_as_int(val[i]));
                }
            }
        }
    }
}

// ---- SpMM fused with in-LDS binning: one block per 64-row bucket -----------
// Phase 1: single global read of meta (staged to LDS raw[] while histing),
//          1-wave shfl scan over 64 bins, LDS->LDS permute into ord[].
// Phase 2: 32 groups x 16 lanes; group owns 2 rows; 4 edges in flight;
//          register accumulation, 32 VGPR (no deeper pipeline: round-4 lesson
//          -- pipelining under the 64-VGPR launch-bounds cap spills to HBM).
__global__ __launch_bounds__(512, 8) void spmm_fused(const unsigned short* __restrict__ h,
                                                     const int* __restrict__ cnt,
                                                     const int2* __restrict__ meta,
                                                     const float* __restrict__ bias,
                                                     float* __restrict__ out) {
    __shared__ int2 raw[CAP];                      // 12 KB
    __shared__ int2 ord[CAP];                      // 12 KB
    __shared__ int hist[64], startS[64], cursor[64];
    const int t = threadIdx.x, b = blockIdx.x;
    const int b0 = b * CAP;
    int n = cnt[b]; if (n > CAP) n = CAP;

    if (t < 64) hist[t] = 0;
    __syncthreads();
    // single global pass: stage + histogram
    for (int i = t; i < n; i += 512) {
        int2 e = meta[b0 + i];
        raw[i] = e;
        atomicAdd(&hist[((unsigned)e.x >> 24) & 63], 1);
    }
    __syncthreads();
    // single-wave exclusive scan over 64 bins
    if (t < 64) {
        int h0 = hist[t];
        int s0 = h0;
        #pragma unroll
        for (int off = 1; off < 64; off <<= 1) {
            int u = __shfl_up(s0, off);
            if (t >= off) s0 += u;
        }
        startS[t] = s0 - h0; cursor[t] = s0 - h0;
    }
    __syncthreads();
    // LDS->LDS permute into row order (strip rl tag from col)
    for (int i = t; i < n; i += 512) {
        int2 e = raw[i];
        int rl = ((unsigned)e.x >> 24) & 63;
        int pos = atomicAdd(&cursor[rl], 1);
        ord[pos] = make_int2(e.x & 0x00FFFFFF, e.y);
    }
    __syncthreads();

    // phase 2: register accumulation over row runs (acc[j] = channel j*16+l16)
    const int lane = t & 63;
    const int l16 = lane & 15;
    const int grp = (t >> 6) * 4 + (lane >> 4);    // 0..31
    const unsigned short* hp = h + l16 * 8;

    #pragma unroll
    for (int j = 0; j < 2; j++) {
        const int rl = grp * 2 + j;
        const int s = startS[rl], d = hist[rl];
        float acc[8];
        #pragma unroll
        for (int k = 0; k < 8; k++) acc[k] = 0.f;
        for (int i = 0; i < d; i += 4) {
            int2 mm[4];
            #pragma unroll
            for (int u = 0; u < 4; u++) {
                int idx = i + u; if (idx > d - 1) idx = d - 1;
                mm[u] = ord[s + idx];
            }
            uint4 hv[4];
            #pragma unroll
            for (int u = 0; u < 4; u++)
                hv[u] = *reinterpret_cast<const uint4*>(hp + (size_t)mm[u].x * F_OUT);
            #pragma unroll
            for (int u = 0; u < 4; u++) {
                float v = (i + u < d) ? __int_as_float(mm[u].y) : 0.f;
                #pragma unroll
                for (int k = 0; k < 4; k++) {
                    unsigned uu = ((const unsigned*)&hv[u])[k];
                    acc[2 * k]     += v * __uint_as_float(uu << 16);
                    acc[2 * k + 1] += v * __uint_as_float(uu & 0xffff0000u);
                }
            }
        }
        const int r = b * 64 + rl;
        if (r < N_NODES) {
            float* op = out + (size_t)r * F_OUT + l16;
            #pragma unroll
            for (int jc = 0; jc < 8; jc++) {
                float o = fmaxf(acc[jc] + bias[jc * 16 + l16], 0.f);
                op[jc * 16] = o;                   // 16 lanes x 4 B = 64 B/instr
            }
        }
    }
}

extern "C" void kernel_launch(void* const* d_in, const int* in_sizes, int n_in,
                              void* d_out, int out_size, void* d_ws, size_t ws_size,
                              hipStream_t stream) {
    const float* x        = (const float*)d_in[0];
    const int*   adj_row  = (const int*)d_in[1];
    const int*   adj_col  = (const int*)d_in[2];
    const float* adj_vals = (const float*)d_in[3];
    const float* w        = (const float*)d_in[4];
    const float* b        = (const float*)d_in[5];
    float* out = (float*)d_out;

    // workspace layout (16B-aligned)
    char* ws = (char*)d_ws;
    unsigned short* wT = (unsigned short*)ws;                          // 64 KB
    unsigned short* h  = (unsigned short*)(ws + 65536);                // 25.6 MB
    size_t off = 65536 + (size_t)N_NODES * F_OUT * 2;                  // 25,665,536
    int2* metabuf = (int2*)(ws + off);  off += (size_t)NB * CAP * 8;   // 19.2 MB
    int* cnt      = (int*)(ws + off);   off += 8192;

    prep_w<<<128, 256, 0, stream>>>(w, wT, cnt);
    fused_mid<<<GEMM_BLOCKS + NBLK, 256, 0, stream>>>(x, wT, h, adj_row, adj_col,
                                                      adj_vals, cnt, metabuf);
    spmm_fused<<<NB, 512, 0, stream>>>(h, cnt, metabuf, b, out);
}

// Round 8
// 286.705 us; speedup vs baseline: 1.0175x; 1.0175x over previous
//
#include <hip/hip_runtime.h>
#include <hip/hip_bf16.h>
#include <cstdint>
#include <cstddef>

#define N_NODES 100000
#define N_EDGES 1600000
#define F_IN 256
#define F_OUT 128

#define NB 1563       // buckets = row >> 6 (64 rows each); 99999>>6 = 1562
#define NBLK 391      // scatter tiles (4096 edges each)
#define TILE 4096     // edges per scatter tile
#define CAP 1536      // fixed metabuf slots per bucket (mean 1024, +16 sigma)
#define GEMM_BLOCKS 782   // 128 rows per GEMM block

typedef __attribute__((ext_vector_type(8))) short short8;
typedef __attribute__((ext_vector_type(4))) float floatx4;

static __device__ __forceinline__ unsigned short f2bf(float f) {
    union { float f; unsigned u; } v; v.f = f;
    unsigned r = v.u + 0x7FFF + ((v.u >> 16) & 1);   // RNE
    return (unsigned short)(r >> 16);
}

// ---- w prep + cnt zero: fp32 [256][128] -> bf16 swizzled wT ----------------
__global__ void prep_w(const float* __restrict__ w, unsigned short* __restrict__ wT,
                       int* __restrict__ cnt) {
    int i = blockIdx.x * 256 + threadIdx.x;   // 0..32767
    int k = i >> 7;
    int n = i & 127;
    int g = (k >> 3) ^ (n & 7);
    wT[n * 256 + g * 8 + (k & 7)] = f2bf(w[i]);
    if (blockIdx.x == 0)
        for (int j = threadIdx.x; j < NB; j += 256) cnt[j] = 0;
}

// ---- fused_mid: blocks [0,782) = GEMM (128 rows), [782,1173) = scatter -----
// Round-7 lesson: occupancy was grid- and VGPR-bound, not LDS-bound (587
// blocks = 2.3/CU; VGPR 124). This round: 1173 blocks (all co-resident,
// scatter overlaps GEMM throughout) and acc[2][8] (64 acc VGPRs, ~100 total).
// GEMM stages w in two 32 KB K-halves (proven round 7): for k>>3 = 16h+m the
// swizzled group g = 16h + (m^(n&7)); half h addressed wlds[n*128 + gl*8 +
// (k&7)], gl=(ksl*4+quad)^(n&7); acc persists across halves.
__global__ __launch_bounds__(256, 2) void fused_mid(const float* __restrict__ x,
                                                    const unsigned short* __restrict__ wT,
                                                    unsigned short* __restrict__ h,
                                                    const int* __restrict__ row,
                                                    const int* __restrict__ col,
                                                    const float* __restrict__ val,
                                                    int* __restrict__ cnt,
                                                    int2* __restrict__ metabuf) {
    __shared__ __align__(16) unsigned short smem[128 * 128];   // 32 KB union
    const int tid = threadIdx.x;

    if (blockIdx.x < GEMM_BLOCKS) {
        unsigned short* wlds = smem;
        const int wave = tid >> 6, lane = tid & 63;
        const int quad = lane >> 4, l16 = lane & 15;
        const int rowbase = blockIdx.x * 128 + wave * 32;

        floatx4 acc[2][8];
        #pragma unroll
        for (int mf = 0; mf < 2; mf++)
            #pragma unroll
            for (int nt = 0; nt < 8; nt++) acc[mf][nt] = (floatx4)0.f;

        #pragma unroll
        for (int half = 0; half < 2; half++) {
            if (half) __syncthreads();             // previous compute done
            {   // stage 32 KB: fx4 j=(n,gl) <- wT fx4 [n*32 + 16*half + gl]
                const floatx4* src = reinterpret_cast<const floatx4*>(wT);
                floatx4* dst = reinterpret_cast<floatx4*>(wlds);
                #pragma unroll
                for (int it = 0; it < 8; it++) {
                    int j = tid + it * 256;        // 0..2047
                    int n = j >> 4, gl = j & 15;
                    dst[j] = src[n * 32 + half * 16 + gl];
                }
            }
            __syncthreads();

            #pragma unroll
            for (int ksl = 0; ksl < 4; ksl++) {
                const int ks = half * 4 + ksl;
                const int k0 = ks * 32 + quad * 8;
                short8 afrag[2];
                #pragma unroll
                for (int mf = 0; mf < 2; mf++) {
                    int r = rowbase + mf * 16 + l16;
                    if (r >= N_NODES) r = N_NODES - 1;
                    const float* xp = x + (size_t)r * F_IN + k0;
                    floatx4 x0 = *reinterpret_cast<const floatx4*>(xp);
                    floatx4 x1 = *reinterpret_cast<const floatx4*>(xp + 4);
                    short8 a;
                    a[0] = (short)f2bf(x0[0]); a[1] = (short)f2bf(x0[1]);
                    a[2] = (short)f2bf(x0[2]); a[3] = (short)f2bf(x0[3]);
                    a[4] = (short)f2bf(x1[0]); a[5] = (short)f2bf(x1[1]);
                    a[6] = (short)f2bf(x1[2]); a[7] = (short)f2bf(x1[3]);
                    afrag[mf] = a;
                }
                short8 bfrag[8];
                const int gql = ksl * 4 + quad;
                #pragma unroll
                for (int nt = 0; nt < 8; nt++) {
                    const int n = nt * 16 + l16;
                    const int gl = gql ^ (n & 7);
                    bfrag[nt] = *reinterpret_cast<const short8*>(&wlds[n * 128 + gl * 8]);
                }
                #pragma unroll
                for (int mf = 0; mf < 2; mf++)
                    #pragma unroll
                    for (int nt = 0; nt < 8; nt++)
                        acc[mf][nt] = __builtin_amdgcn_mfma_f32_16x16x32_bf16(
                            afrag[mf], bfrag[nt], acc[mf][nt], 0, 0, 0);
            }
        }

        #pragma unroll
        for (int mf = 0; mf < 2; mf++) {
            const int mbase = rowbase + mf * 16 + quad * 4;
            #pragma unroll
            for (int reg = 0; reg < 4; reg++) {
                const int m = mbase + reg;
                if (m < N_NODES) {
                    short8 hv;
                    #pragma unroll
                    for (int nt = 0; nt < 8; nt++) hv[nt] = (short)f2bf(acc[mf][nt][reg]);
                    *reinterpret_cast<short8*>(&h[(size_t)m * F_OUT + l16 * 8]) = hv;
                }
            }
        }
    } else {
        // ---- scatter half (needs 2*NB*4 = 12.5 KB of smem) ----
        int* hist   = reinterpret_cast<int*>(smem);        // NB ints
        int* cursor = hist + NB;                           // NB ints
        const int blk = blockIdx.x - GEMM_BLOCKS;
        for (int i = tid; i < NB; i += 256) hist[i] = 0;
        __syncthreads();
        const long tb = (long)blk * TILE;
        // pass 1: histogram over row
        #pragma unroll
        for (int c = 0; c < 4; c++) {
            long i0 = tb + c * 1024 + tid * 4;
            if (i0 + 4 <= N_EDGES) {
                int4 r = *reinterpret_cast<const int4*>(row + i0);
                atomicAdd(&hist[r.x >> 6], 1); atomicAdd(&hist[r.y >> 6], 1);
                atomicAdd(&hist[r.z >> 6], 1); atomicAdd(&hist[r.w >> 6], 1);
            } else {
                for (long i = i0; i < N_EDGES && i < i0 + 4; i++)
                    atomicAdd(&hist[row[i] >> 6], 1);
            }
        }
        __syncthreads();
        // reserve global ranges (one atomic per touched bin)
        for (int bin = tid; bin < NB; bin += 256) {
            int hc = hist[bin];
            int base = bin * CAP;
            if (hc) base += atomicAdd(&cnt[bin], hc);
            cursor[bin] = base;
        }
        __syncthreads();
        // pass 2: write edges (row re-read is L2-hot)
        #pragma unroll
        for (int c = 0; c < 4; c++) {
            long i0 = tb + c * 1024 + tid * 4;
            if (i0 + 4 <= N_EDGES) {
                int4 r  = *reinterpret_cast<const int4*>(row + i0);
                int4 cc = *reinterpret_cast<const int4*>(col + i0);
                floatx4 vv = *reinterpret_cast<const floatx4*>(val + i0);
                int rr[4] = {r.x, r.y, r.z, r.w};
                int c4[4] = {cc.x, cc.y, cc.z, cc.w};
                float v4[4] = {vv[0], vv[1], vv[2], vv[3]};
                #pragma unroll
                for (int j = 0; j < 4; j++) {
                    int bin = rr[j] >> 6, rl = rr[j] & 63;
                    int pos = atomicAdd(&cursor[bin], 1);
                    if (pos < (bin + 1) * CAP)
                        metabuf[pos] = make_int2(c4[j] | (rl << 24), __float_as_int(v4[j]));
                }
            } else {
                for (long i = i0; i < N_EDGES && i < i0 + 4; i++) {
                    int rv = row[i];
                    int bin = rv >> 6, rl = rv & 63;
                    int pos = atomicAdd(&cursor[bin], 1);
                    if (pos < (bin + 1) * CAP)
                        metabuf[pos] = make_int2(col[i] | (rl << 24), __float_as_int(val[i]));
                }
            }
        }
    }
}

// ---- SpMM fused with in-LDS binning: one block per 64-row bucket -----------
// Phase 1: single global read of meta (staged to LDS raw[] while histing),
//          1-wave shfl scan over 64 bins, LDS->LDS permute into ord[].
// Phase 2: 32 groups x 16 lanes; group owns 2 rows; 4 edges in flight;
//          register accumulation, 32 VGPR (no deeper pipeline: round-4 lesson
//          -- pipelining under the 64-VGPR launch-bounds cap spills to HBM).
__global__ __launch_bounds__(512, 8) void spmm_fused(const unsigned short* __restrict__ h,
                                                     const int* __restrict__ cnt,
                                                     const int2* __restrict__ meta,
                                                     const float* __restrict__ bias,
                                                     float* __restrict__ out) {
    __shared__ int2 raw[CAP];                      // 12 KB
    __shared__ int2 ord[CAP];                      // 12 KB
    __shared__ int hist[64], startS[64], cursor[64];
    const int t = threadIdx.x, b = blockIdx.x;
    const int b0 = b * CAP;
    int n = cnt[b]; if (n > CAP) n = CAP;

    if (t < 64) hist[t] = 0;
    __syncthreads();
    // single global pass: stage + histogram
    for (int i = t; i < n; i += 512) {
        int2 e = meta[b0 + i];
        raw[i] = e;
        atomicAdd(&hist[((unsigned)e.x >> 24) & 63], 1);
    }
    __syncthreads();
    // single-wave exclusive scan over 64 bins
    if (t < 64) {
        int h0 = hist[t];
        int s0 = h0;
        #pragma unroll
        for (int off = 1; off < 64; off <<= 1) {
            int u = __shfl_up(s0, off);
            if (t >= off) s0 += u;
        }
        startS[t] = s0 - h0; cursor[t] = s0 - h0;
    }
    __syncthreads();
    // LDS->LDS permute into row order (strip rl tag from col)
    for (int i = t; i < n; i += 512) {
        int2 e = raw[i];
        int rl = ((unsigned)e.x >> 24) & 63;
        int pos = atomicAdd(&cursor[rl], 1);
        ord[pos] = make_int2(e.x & 0x00FFFFFF, e.y);
    }
    __syncthreads();

    // phase 2: register accumulation over row runs (acc[j] = channel j*16+l16)
    const int lane = t & 63;
    const int l16 = lane & 15;
    const int grp = (t >> 6) * 4 + (lane >> 4);    // 0..31
    const unsigned short* hp = h + l16 * 8;

    #pragma unroll
    for (int j = 0; j < 2; j++) {
        const int rl = grp * 2 + j;
        const int s = startS[rl], d = hist[rl];
        float acc[8];
        #pragma unroll
        for (int k = 0; k < 8; k++) acc[k] = 0.f;
        for (int i = 0; i < d; i += 4) {
            int2 mm[4];
            #pragma unroll
            for (int u = 0; u < 4; u++) {
                int idx = i + u; if (idx > d - 1) idx = d - 1;
                mm[u] = ord[s + idx];
            }
            uint4 hv[4];
            #pragma unroll
            for (int u = 0; u < 4; u++)
                hv[u] = *reinterpret_cast<const uint4*>(hp + (size_t)mm[u].x * F_OUT);
            #pragma unroll
            for (int u = 0; u < 4; u++) {
                float v = (i + u < d) ? __int_as_float(mm[u].y) : 0.f;
                #pragma unroll
                for (int k = 0; k < 4; k++) {
                    unsigned uu = ((const unsigned*)&hv[u])[k];
                    acc[2 * k]     += v * __uint_as_float(uu << 16);
                    acc[2 * k + 1] += v * __uint_as_float(uu & 0xffff0000u);
                }
            }
        }
        const int r = b * 64 + rl;
        if (r < N_NODES) {
            float* op = out + (size_t)r * F_OUT + l16;
            #pragma unroll
            for (int jc = 0; jc < 8; jc++) {
                float o = fmaxf(acc[jc] + bias[jc * 16 + l16], 0.f);
                op[jc * 16] = o;                   // 16 lanes x 4 B = 64 B/instr
            }
        }
    }
}

extern "C" void kernel_launch(void* const* d_in, const int* in_sizes, int n_in,
                              void* d_out, int out_size, void* d_ws, size_t ws_size,
                              hipStream_t stream) {
    const float* x        = (const float*)d_in[0];
    const int*   adj_row  = (const int*)d_in[1];
    const int*   adj_col  = (const int*)d_in[2];
    const float* adj_vals = (const float*)d_in[3];
    const float* w        = (const float*)d_in[4];
    const float* b        = (const float*)d_in[5];
    float* out = (float*)d_out;

    // workspace layout (16B-aligned)
    char* ws = (char*)d_ws;
    unsigned short* wT = (unsigned short*)ws;                          // 64 KB
    unsigned short* h  = (unsigned short*)(ws + 65536);                // 25.6 MB
    size_t off = 65536 + (size_t)N_NODES * F_OUT * 2;                  // 25,665,536
    int2* metabuf = (int2*)(ws + off);  off += (size_t)NB * CAP * 8;   // 19.2 MB
    int* cnt      = (int*)(ws + off);   off += 8192;

    prep_w<<<128, 256, 0, stream>>>(w, wT, cnt);
    fused_mid<<<GEMM_BLOCKS + NBLK, 256, 0, stream>>>(x, wT, h, adj_row, adj_col,
                                                      adj_vals, cnt, metabuf);
    spmm_fused<<<NB, 512, 0, stream>>>(h, cnt, metabuf, b, out);
}

// Round 9
// 265.519 us; speedup vs baseline: 1.0987x; 1.0798x over previous
//
#include <hip/hip_runtime.h>
#include <hip/hip_bf16.h>
#include <cstdint>
#include <cstddef>

#define N_NODES 100000
#define N_EDGES 1600000
#define F_IN 256
#define F_OUT 128

#define NB 1563       // buckets = row >> 6 (64 rows each); 99999>>6 = 1562
#define NBLK 391      // scatter tiles (4096 edges each)
#define TILE 4096     // edges per scatter tile
#define CAP 1536      // fixed metabuf slots per bucket (mean 1024, +16 sigma)
#define GEMM_BLOCKS 391   // 256 rows per GEMM block (512 threads, 8 waves)

typedef __attribute__((ext_vector_type(8))) short short8;
typedef __attribute__((ext_vector_type(4))) float floatx4;

static __device__ __forceinline__ unsigned short f2bf(float f) {
    union { float f; unsigned u; } v; v.f = f;
    unsigned r = v.u + 0x7FFF + ((v.u >> 16) & 1);   // RNE
    return (unsigned short)(r >> 16);
}

// ---- w prep + cnt zero: fp32 [256][128] -> bf16 swizzled wT ----------------
__global__ void prep_w(const float* __restrict__ w, unsigned short* __restrict__ wT,
                       int* __restrict__ cnt) {
    int i = blockIdx.x * 256 + threadIdx.x;   // 0..32767
    int k = i >> 7;
    int n = i & 127;
    int g = (k >> 3) ^ (n & 7);
    wT[n * 256 + g * 8 + (k & 7)] = f2bf(w[i]);
    if (blockIdx.x == 0)
        for (int j = threadIdx.x; j < NB; j += 256) cnt[j] = 0;
}

// ---- fused_mid: blocks [0,391) = GEMM (256 rows), [391,782) = scatter ------
// Round-8 lesson: occupancy was capped by the scatter half's serial depth
// (16 edges/thread at ~6 waves/CU after GEMM drained), not by grid size.
// This round: 512 threads/block for both halves -> scatter is 8 edges/thread
// and holds 2x the waves; 782 blocks ~ 3/CU, all resident from t=0.
// GEMM stages w in two 32 KB K-halves (proven r7/r8): for k>>3 = 16h+m the
// swizzled group g = 16h + (m^(n&7)); half h addressed wlds[n*128 + gl*8 +
// (k&7)], gl=(ksl*4+quad)^(n&7); acc persists across halves.
__global__ __launch_bounds__(512, 2) void fused_mid(const float* __restrict__ x,
                                                    const unsigned short* __restrict__ wT,
                                                    unsigned short* __restrict__ h,
                                                    const int* __restrict__ row,
                                                    const int* __restrict__ col,
                                                    const float* __restrict__ val,
                                                    int* __restrict__ cnt,
                                                    int2* __restrict__ metabuf) {
    __shared__ __align__(16) unsigned short smem[128 * 128];   // 32 KB union
    const int tid = threadIdx.x;

    if (blockIdx.x < GEMM_BLOCKS) {
        unsigned short* wlds = smem;
        const int wave = tid >> 6, lane = tid & 63;
        const int quad = lane >> 4, l16 = lane & 15;
        const int rowbase = blockIdx.x * 256 + wave * 32;

        floatx4 acc[2][8];
        #pragma unroll
        for (int mf = 0; mf < 2; mf++)
            #pragma unroll
            for (int nt = 0; nt < 8; nt++) acc[mf][nt] = (floatx4)0.f;

        #pragma unroll
        for (int half = 0; half < 2; half++) {
            if (half) __syncthreads();             // previous compute done
            {   // stage 32 KB: fx4 j=(n,gl) <- wT fx4 [n*32 + 16*half + gl]
                const floatx4* src = reinterpret_cast<const floatx4*>(wT);
                floatx4* dst = reinterpret_cast<floatx4*>(wlds);
                #pragma unroll
                for (int it = 0; it < 4; it++) {
                    int j = tid + it * 512;        // 0..2047
                    int n = j >> 4, gl = j & 15;
                    dst[j] = src[n * 32 + half * 16 + gl];
                }
            }
            __syncthreads();

            #pragma unroll
            for (int ksl = 0; ksl < 4; ksl++) {
                const int ks = half * 4 + ksl;
                const int k0 = ks * 32 + quad * 8;
                short8 afrag[2];
                #pragma unroll
                for (int mf = 0; mf < 2; mf++) {
                    int r = rowbase + mf * 16 + l16;
                    if (r >= N_NODES) r = N_NODES - 1;
                    const float* xp = x + (size_t)r * F_IN + k0;
                    floatx4 x0 = *reinterpret_cast<const floatx4*>(xp);
                    floatx4 x1 = *reinterpret_cast<const floatx4*>(xp + 4);
                    short8 a;
                    a[0] = (short)f2bf(x0[0]); a[1] = (short)f2bf(x0[1]);
                    a[2] = (short)f2bf(x0[2]); a[3] = (short)f2bf(x0[3]);
                    a[4] = (short)f2bf(x1[0]); a[5] = (short)f2bf(x1[1]);
                    a[6] = (short)f2bf(x1[2]); a[7] = (short)f2bf(x1[3]);
                    afrag[mf] = a;
                }
                short8 bfrag[8];
                const int gql = ksl * 4 + quad;
                #pragma unroll
                for (int nt = 0; nt < 8; nt++) {
                    const int n = nt * 16 + l16;
                    const int gl = gql ^ (n & 7);
                    bfrag[nt] = *reinterpret_cast<const short8*>(&wlds[n * 128 + gl * 8]);
                }
                #pragma unroll
                for (int mf = 0; mf < 2; mf++)
                    #pragma unroll
                    for (int nt = 0; nt < 8; nt++)
                        acc[mf][nt] = __builtin_amdgcn_mfma_f32_16x16x32_bf16(
                            afrag[mf], bfrag[nt], acc[mf][nt], 0, 0, 0);
            }
        }

        #pragma unroll
        for (int mf = 0; mf < 2; mf++) {
            const int mbase = rowbase + mf * 16 + quad * 4;
            #pragma unroll
            for (int reg = 0; reg < 4; reg++) {
                const int m = mbase + reg;
                if (m < N_NODES) {
                    short8 hv;
                    #pragma unroll
                    for (int nt = 0; nt < 8; nt++) hv[nt] = (short)f2bf(acc[mf][nt][reg]);
                    *reinterpret_cast<short8*>(&h[(size_t)m * F_OUT + l16 * 8]) = hv;
                }
            }
        }
    } else {
        // ---- scatter half (needs 2*NB*4 = 12.5 KB of smem) ----
        int* hist   = reinterpret_cast<int*>(smem);        // NB ints
        int* cursor = hist + NB;                           // NB ints
        const int blk = blockIdx.x - GEMM_BLOCKS;
        for (int i = tid; i < NB; i += 512) hist[i] = 0;
        __syncthreads();
        const long tb = (long)blk * TILE;
        // pass 1: histogram over row (8 edges/thread)
        #pragma unroll
        for (int c = 0; c < 2; c++) {
            long i0 = tb + c * 2048 + tid * 4;
            if (i0 + 4 <= N_EDGES) {
                int4 r = *reinterpret_cast<const int4*>(row + i0);
                atomicAdd(&hist[r.x >> 6], 1); atomicAdd(&hist[r.y >> 6], 1);
                atomicAdd(&hist[r.z >> 6], 1); atomicAdd(&hist[r.w >> 6], 1);
            } else {
                for (long i = i0; i < N_EDGES && i < i0 + 4; i++)
                    atomicAdd(&hist[row[i] >> 6], 1);
            }
        }
        __syncthreads();
        // reserve global ranges (one atomic per touched bin)
        for (int bin = tid; bin < NB; bin += 512) {
            int hc = hist[bin];
            int base = bin * CAP;
            if (hc) base += atomicAdd(&cnt[bin], hc);
            cursor[bin] = base;
        }
        __syncthreads();
        // pass 2: write edges (row re-read is L2-hot)
        #pragma unroll
        for (int c = 0; c < 2; c++) {
            long i0 = tb + c * 2048 + tid * 4;
            if (i0 + 4 <= N_EDGES) {
                int4 r  = *reinterpret_cast<const int4*>(row + i0);
                int4 cc = *reinterpret_cast<const int4*>(col + i0);
                floatx4 vv = *reinterpret_cast<const floatx4*>(val + i0);
                int rr[4] = {r.x, r.y, r.z, r.w};
                int c4[4] = {cc.x, cc.y, cc.z, cc.w};
                float v4[4] = {vv[0], vv[1], vv[2], vv[3]};
                #pragma unroll
                for (int j = 0; j < 4; j++) {
                    int bin = rr[j] >> 6, rl = rr[j] & 63;
                    int pos = atomicAdd(&cursor[bin], 1);
                    if (pos < (bin + 1) * CAP)
                        metabuf[pos] = make_int2(c4[j] | (rl << 24), __float_as_int(v4[j]));
                }
            } else {
                for (long i = i0; i < N_EDGES && i < i0 + 4; i++) {
                    int rv = row[i];
                    int bin = rv >> 6, rl = rv & 63;
                    int pos = atomicAdd(&cursor[bin], 1);
                    if (pos < (bin + 1) * CAP)
                        metabuf[pos] = make_int2(col[i] | (rl << 24), __float_as_int(val[i]));
                }
            }
        }
    }
}

// ---- SpMM fused with in-LDS binning: one block per 64-row bucket -----------
// Phase 1: single global read of meta (staged to LDS raw[] while histing),
//          1-wave shfl scan over 64 bins, LDS->LDS permute into ord[].
// Phase 2: 32 groups x 16 lanes; group owns 2 rows; 4 edges in flight;
//          register accumulation, 32 VGPR (no deeper pipeline: round-4 lesson
//          -- pipelining under the 64-VGPR launch-bounds cap spills to HBM).
__global__ __launch_bounds__(512, 8) void spmm_fused(const unsigned short* __restrict__ h,
                                                     const int* __restrict__ cnt,
                                                     const int2* __restrict__ meta,
                                                     const float* __restrict__ bias,
                                                     float* __restrict__ out) {
    __shared__ int2 raw[CAP];                      // 12 KB
    __shared__ int2 ord[CAP];                      // 12 KB
    __shared__ int hist[64], startS[64], cursor[64];
    const int t = threadIdx.x, b = blockIdx.x;
    const int b0 = b * CAP;
    int n = cnt[b]; if (n > CAP) n = CAP;

    if (t < 64) hist[t] = 0;
    __syncthreads();
    // single global pass: stage + histogram
    for (int i = t; i < n; i += 512) {
        int2 e = meta[b0 + i];
        raw[i] = e;
        atomicAdd(&hist[((unsigned)e.x >> 24) & 63], 1);
    }
    __syncthreads();
    // single-wave exclusive scan over 64 bins
    if (t < 64) {
        int h0 = hist[t];
        int s0 = h0;
        #pragma unroll
        for (int off = 1; off < 64; off <<= 1) {
            int u = __shfl_up(s0, off);
            if (t >= off) s0 += u;
        }
        startS[t] = s0 - h0; cursor[t] = s0 - h0;
    }
    __syncthreads();
    // LDS->LDS permute into row order (strip rl tag from col)
    for (int i = t; i < n; i += 512) {
        int2 e = raw[i];
        int rl = ((unsigned)e.x >> 24) & 63;
        int pos = atomicAdd(&cursor[rl], 1);
        ord[pos] = make_int2(e.x & 0x00FFFFFF, e.y);
    }
    __syncthreads();

    // phase 2: register accumulation over row runs (acc[j] = channel j*16+l16)
    const int lane = t & 63;
    const int l16 = lane & 15;
    const int grp = (t >> 6) * 4 + (lane >> 4);    // 0..31
    const unsigned short* hp = h + l16 * 8;

    #pragma unroll
    for (int j = 0; j < 2; j++) {
        const int rl = grp * 2 + j;
        const int s = startS[rl], d = hist[rl];
        float acc[8];
        #pragma unroll
        for (int k = 0; k < 8; k++) acc[k] = 0.f;
        for (int i = 0; i < d; i += 4) {
            int2 mm[4];
            #pragma unroll
            for (int u = 0; u < 4; u++) {
                int idx = i + u; if (idx > d - 1) idx = d - 1;
                mm[u] = ord[s + idx];
            }
            uint4 hv[4];
            #pragma unroll
            for (int u = 0; u < 4; u++)
                hv[u] = *reinterpret_cast<const uint4*>(hp + (size_t)mm[u].x * F_OUT);
            #pragma unroll
            for (int u = 0; u < 4; u++) {
                float v = (i + u < d) ? __int_as_float(mm[u].y) : 0.f;
                #pragma unroll
                for (int k = 0; k < 4; k++) {
                    unsigned uu = ((const unsigned*)&hv[u])[k];
                    acc[2 * k]     += v * __uint_as_float(uu << 16);
                    acc[2 * k + 1] += v * __uint_as_float(uu & 0xffff0000u);
                }
            }
        }
        const int r = b * 64 + rl;
        if (r < N_NODES) {
            float* op = out + (size_t)r * F_OUT + l16;
            #pragma unroll
            for (int jc = 0; jc < 8; jc++) {
                float o = fmaxf(acc[jc] + bias[jc * 16 + l16], 0.f);
                op[jc * 16] = o;                   // 16 lanes x 4 B = 64 B/instr
            }
        }
    }
}

extern "C" void kernel_launch(void* const* d_in, const int* in_sizes, int n_in,
                              void* d_out, int out_size, void* d_ws, size_t ws_size,
                              hipStream_t stream) {
    const float* x        = (const float*)d_in[0];
    const int*   adj_row  = (const int*)d_in[1];
    const int*   adj_col  = (const int*)d_in[2];
    const float* adj_vals = (const float*)d_in[3];
    const float* w        = (const float*)d_in[4];
    const float* b        = (const float*)d_in[5];
    float* out = (float*)d_out;

    // workspace layout (16B-aligned)
    char* ws = (char*)d_ws;
    unsigned short* wT = (unsigned short*)ws;                          // 64 KB
    unsigned short* h  = (unsigned short*)(ws + 65536);                // 25.6 MB
    size_t off = 65536 + (size_t)N_NODES * F_OUT * 2;                  // 25,665,536
    int2* metabuf = (int2*)(ws + off);  off += (size_t)NB * CAP * 8;   // 19.2 MB
    int* cnt      = (int*)(ws + off);   off += 8192;

    prep_w<<<128, 256, 0, stream>>>(w, wT, cnt);
    fused_mid<<<GEMM_BLOCKS + NBLK, 512, 0, stream>>>(x, wT, h, adj_row, adj_col,
                                                      adj_vals, cnt, metabuf);
    spmm_fused<<<NB, 512, 0, stream>>>(h, cnt, metabuf, b, out);
}

// Round 10
// 261.638 us; speedup vs baseline: 1.1150x; 1.0148x over previous
//
#include <hip/hip_runtime.h>
#include <hip/hip_bf16.h>
#include <cstdint>
#include <cstddef>

#define N_NODES 100000
#define N_EDGES 1600000
#define F_IN 256
#define F_OUT 128

#define NB 1563       // buckets = row >> 6 (64 rows each); 99999>>6 = 1562
#define NBLK 782      // scatter tiles (2048 edges each)
#define TILE 2048     // edges per scatter tile
#define CAP 1536      // fixed metabuf slots per bucket (mean 1024, +16 sigma)
#define GEMM_BLOCKS 391   // 256 rows per GEMM block (512 threads, 8 waves)

typedef __attribute__((ext_vector_type(8))) short short8;
typedef __attribute__((ext_vector_type(4))) float floatx4;

static __device__ __forceinline__ unsigned short f2bf(float f) {
    union { float f; unsigned u; } v; v.f = f;
    unsigned r = v.u + 0x7FFF + ((v.u >> 16) & 1);   // RNE
    return (unsigned short)(r >> 16);
}

// ---- w prep + cnt zero: fp32 [256][128] -> bf16 swizzled wT ----------------
__global__ void prep_w(const float* __restrict__ w, unsigned short* __restrict__ wT,
                       int* __restrict__ cnt) {
    int i = blockIdx.x * 256 + threadIdx.x;   // 0..32767
    int k = i >> 7;
    int n = i & 127;
    int g = (k >> 3) ^ (n & 7);
    wT[n * 256 + g * 8 + (k & 7)] = f2bf(w[i]);
    if (blockIdx.x == 0)
        for (int j = threadIdx.x; j < NB; j += 256) cnt[j] = 0;
}

// ---- fused_mid: blocks [0,391) = GEMM (256 rows), [391,1173) = scatter -----
// Round-9 evidence: scatter serial depth is the live lever (16->8 edges/thread
// gave -23 us). This round: TILE 2048 -> 4 edges/thread (one 4-edge burst per
// pass). Deliberate A/B vs atomic count: reserve atomics rise ~611K->~900K;
// if this rounds nulls, depth is exhausted and atomics/GEMM-latency are the
// residual (pre-committed next step: split kernels to profile halves).
// GEMM stages w in two 32 KB K-halves (proven r7-r9): for k>>3 = 16h+m the
// swizzled group g = 16h + (m^(n&7)); half h addressed wlds[n*128 + gl*8 +
// (k&7)], gl=(ksl*4+quad)^(n&7); acc persists across halves.
__global__ __launch_bounds__(512, 2) void fused_mid(const float* __restrict__ x,
                                                    const unsigned short* __restrict__ wT,
                                                    unsigned short* __restrict__ h,
                                                    const int* __restrict__ row,
                                                    const int* __restrict__ col,
                                                    const float* __restrict__ val,
                                                    int* __restrict__ cnt,
                                                    int2* __restrict__ metabuf) {
    __shared__ __align__(16) unsigned short smem[128 * 128];   // 32 KB union
    const int tid = threadIdx.x;

    if (blockIdx.x < GEMM_BLOCKS) {
        unsigned short* wlds = smem;
        const int wave = tid >> 6, lane = tid & 63;
        const int quad = lane >> 4, l16 = lane & 15;
        const int rowbase = blockIdx.x * 256 + wave * 32;

        floatx4 acc[2][8];
        #pragma unroll
        for (int mf = 0; mf < 2; mf++)
            #pragma unroll
            for (int nt = 0; nt < 8; nt++) acc[mf][nt] = (floatx4)0.f;

        #pragma unroll
        for (int half = 0; half < 2; half++) {
            if (half) __syncthreads();             // previous compute done
            {   // stage 32 KB: fx4 j=(n,gl) <- wT fx4 [n*32 + 16*half + gl]
                const floatx4* src = reinterpret_cast<const floatx4*>(wT);
                floatx4* dst = reinterpret_cast<floatx4*>(wlds);
                #pragma unroll
                for (int it = 0; it < 4; it++) {
                    int j = tid + it * 512;        // 0..2047
                    int n = j >> 4, gl = j & 15;
                    dst[j] = src[n * 32 + half * 16 + gl];
                }
            }
            __syncthreads();

            #pragma unroll
            for (int ksl = 0; ksl < 4; ksl++) {
                const int ks = half * 4 + ksl;
                const int k0 = ks * 32 + quad * 8;
                short8 afrag[2];
                #pragma unroll
                for (int mf = 0; mf < 2; mf++) {
                    int r = rowbase + mf * 16 + l16;
                    if (r >= N_NODES) r = N_NODES - 1;
                    const float* xp = x + (size_t)r * F_IN + k0;
                    floatx4 x0 = *reinterpret_cast<const floatx4*>(xp);
                    floatx4 x1 = *reinterpret_cast<const floatx4*>(xp + 4);
                    short8 a;
                    a[0] = (short)f2bf(x0[0]); a[1] = (short)f2bf(x0[1]);
                    a[2] = (short)f2bf(x0[2]); a[3] = (short)f2bf(x0[3]);
                    a[4] = (short)f2bf(x1[0]); a[5] = (short)f2bf(x1[1]);
                    a[6] = (short)f2bf(x1[2]); a[7] = (short)f2bf(x1[3]);
                    afrag[mf] = a;
                }
                short8 bfrag[8];
                const int gql = ksl * 4 + quad;
                #pragma unroll
                for (int nt = 0; nt < 8; nt++) {
                    const int n = nt * 16 + l16;
                    const int gl = gql ^ (n & 7);
                    bfrag[nt] = *reinterpret_cast<const short8*>(&wlds[n * 128 + gl * 8]);
                }
                #pragma unroll
                for (int mf = 0; mf < 2; mf++)
                    #pragma unroll
                    for (int nt = 0; nt < 8; nt++)
                        acc[mf][nt] = __builtin_amdgcn_mfma_f32_16x16x32_bf16(
                            afrag[mf], bfrag[nt], acc[mf][nt], 0, 0, 0);
            }
        }

        #pragma unroll
        for (int mf = 0; mf < 2; mf++) {
            const int mbase = rowbase + mf * 16 + quad * 4;
            #pragma unroll
            for (int reg = 0; reg < 4; reg++) {
                const int m = mbase + reg;
                if (m < N_NODES) {
                    short8 hv;
                    #pragma unroll
                    for (int nt = 0; nt < 8; nt++) hv[nt] = (short)f2bf(acc[mf][nt][reg]);
                    *reinterpret_cast<short8*>(&h[(size_t)m * F_OUT + l16 * 8]) = hv;
                }
            }
        }
    } else {
        // ---- scatter half (needs 2*NB*4 = 12.5 KB of smem) ----
        int* hist   = reinterpret_cast<int*>(smem);        // NB ints
        int* cursor = hist + NB;                           // NB ints
        const int blk = blockIdx.x - GEMM_BLOCKS;
        for (int i = tid; i < NB; i += 512) hist[i] = 0;
        __syncthreads();
        const long tb = (long)blk * TILE;
        // pass 1: histogram over row (4 edges/thread, one burst)
        {
            long i0 = tb + tid * 4;
            if (i0 + 4 <= N_EDGES) {
                int4 r = *reinterpret_cast<const int4*>(row + i0);
                atomicAdd(&hist[r.x >> 6], 1); atomicAdd(&hist[r.y >> 6], 1);
                atomicAdd(&hist[r.z >> 6], 1); atomicAdd(&hist[r.w >> 6], 1);
            } else {
                for (long i = i0; i < N_EDGES && i < i0 + 4; i++)
                    atomicAdd(&hist[row[i] >> 6], 1);
            }
        }
        __syncthreads();
        // reserve global ranges (one atomic per touched bin)
        for (int bin = tid; bin < NB; bin += 512) {
            int hc = hist[bin];
            int base = bin * CAP;
            if (hc) base += atomicAdd(&cnt[bin], hc);
            cursor[bin] = base;
        }
        __syncthreads();
        // pass 2: write edges (row re-read is L2-hot)
        {
            long i0 = tb + tid * 4;
            if (i0 + 4 <= N_EDGES) {
                int4 r  = *reinterpret_cast<const int4*>(row + i0);
                int4 cc = *reinterpret_cast<const int4*>(col + i0);
                floatx4 vv = *reinterpret_cast<const floatx4*>(val + i0);
                int rr[4] = {r.x, r.y, r.z, r.w};
                int c4[4] = {cc.x, cc.y, cc.z, cc.w};
                float v4[4] = {vv[0], vv[1], vv[2], vv[3]};
                #pragma unroll
                for (int j = 0; j < 4; j++) {
                    int bin = rr[j] >> 6, rl = rr[j] & 63;
                    int pos = atomicAdd(&cursor[bin], 1);
                    if (pos < (bin + 1) * CAP)
                        metabuf[pos] = make_int2(c4[j] | (rl << 24), __float_as_int(v4[j]));
                }
            } else {
                for (long i = i0; i < N_EDGES && i < i0 + 4; i++) {
                    int rv = row[i];
                    int bin = rv >> 6, rl = rv & 63;
                    int pos = atomicAdd(&cursor[bin], 1);
                    if (pos < (bin + 1) * CAP)
                        metabuf[pos] = make_int2(col[i] | (rl << 24), __float_as_int(val[i]));
                }
            }
        }
    }
}

// ---- SpMM fused with in-LDS binning: one block per 64-row bucket -----------
// Phase 1: single global read of meta (staged to LDS raw[] while histing),
//          1-wave shfl scan over 64 bins, LDS->LDS permute into ord[].
// Phase 2: 32 groups x 16 lanes; group owns 2 rows; 4 edges in flight;
//          register accumulation, 32 VGPR (no deeper pipeline: round-4 lesson
//          -- pipelining under the 64-VGPR launch-bounds cap spills to HBM).
__global__ __launch_bounds__(512, 8) void spmm_fused(const unsigned short* __restrict__ h,
                                                     const int* __restrict__ cnt,
                                                     const int2* __restrict__ meta,
                                                     const float* __restrict__ bias,
                                                     float* __restrict__ out) {
    __shared__ int2 raw[CAP];                      // 12 KB
    __shared__ int2 ord[CAP];                      // 12 KB
    __shared__ int hist[64], startS[64], cursor[64];
    const int t = threadIdx.x, b = blockIdx.x;
    const int b0 = b * CAP;
    int n = cnt[b]; if (n > CAP) n = CAP;

    if (t < 64) hist[t] = 0;
    __syncthreads();
    // single global pass: stage + histogram
    for (int i = t; i < n; i += 512) {
        int2 e = meta[b0 + i];
        raw[i] = e;
        atomicAdd(&hist[((unsigned)e.x >> 24) & 63], 1);
    }
    __syncthreads();
    // single-wave exclusive scan over 64 bins
    if (t < 64) {
        int h0 = hist[t];
        int s0 = h0;
        #pragma unroll
        for (int off = 1; off < 64; off <<= 1) {
            int u = __shfl_up(s0, off);
            if (t >= off) s0 += u;
        }
        startS[t] = s0 - h0; cursor[t] = s0 - h0;
    }
    __syncthreads();
    // LDS->LDS permute into row order (strip rl tag from col)
    for (int i = t; i < n; i += 512) {
        int2 e = raw[i];
        int rl = ((unsigned)e.x >> 24) & 63;
        int pos = atomicAdd(&cursor[rl], 1);
        ord[pos] = make_int2(e.x & 0x00FFFFFF, e.y);
    }
    __syncthreads();

    // phase 2: register accumulation over row runs (acc[j] = channel j*16+l16)
    const int lane = t & 63;
    const int l16 = lane & 15;
    const int grp = (t >> 6) * 4 + (lane >> 4);    // 0..31
    const unsigned short* hp = h + l16 * 8;

    #pragma unroll
    for (int j = 0; j < 2; j++) {
        const int rl = grp * 2 + j;
        const int s = startS[rl], d = hist[rl];
        float acc[8];
        #pragma unroll
        for (int k = 0; k < 8; k++) acc[k] = 0.f;
        for (int i = 0; i < d; i += 4) {
            int2 mm[4];
            #pragma unroll
            for (int u = 0; u < 4; u++) {
                int idx = i + u; if (idx > d - 1) idx = d - 1;
                mm[u] = ord[s + idx];
            }
            uint4 hv[4];
            #pragma unroll
            for (int u = 0; u < 4; u++)
                hv[u] = *reinterpret_cast<const uint4*>(hp + (size_t)mm[u].x * F_OUT);
            #pragma unroll
            for (int u = 0; u < 4; u++) {
                float v = (i + u < d) ? __int_as_float(mm[u].y) : 0.f;
                #pragma unroll
                for (int k = 0; k < 4; k++) {
                    unsigned uu = ((const unsigned*)&hv[u])[k];
                    acc[2 * k]     += v * __uint_as_float(uu << 16);
                    acc[2 * k + 1] += v * __uint_as_float(uu & 0xffff0000u);
                }
            }
        }
        const int r = b * 64 + rl;
        if (r < N_NODES) {
            float* op = out + (size_t)r * F_OUT + l16;
            #pragma unroll
            for (int jc = 0; jc < 8; jc++) {
                float o = fmaxf(acc[jc] + bias[jc * 16 + l16], 0.f);
                op[jc * 16] = o;                   // 16 lanes x 4 B = 64 B/instr
            }
        }
    }
}

extern "C" void kernel_launch(void* const* d_in, const int* in_sizes, int n_in,
                              void* d_out, int out_size, void* d_ws, size_t ws_size,
                              hipStream_t stream) {
    const float* x        = (const float*)d_in[0];
    const int*   adj_row  = (const int*)d_in[1];
    const int*   adj_col  = (const int*)d_in[2];
    const float* adj_vals = (const float*)d_in[3];
    const float* w        = (const float*)d_in[4];
    const float* b        = (const float*)d_in[5];
    float* out = (float*)d_out;

    // workspace layout (16B-aligned)
    char* ws = (char*)d_ws;
    unsigned short* wT = (unsigned short*)ws;                          // 64 KB
    unsigned short* h  = (unsigned short*)(ws + 65536);                // 25.6 MB
    size_t off = 65536 + (size_t)N_NODES * F_OUT * 2;                  // 25,665,536
    int2* metabuf = (int2*)(ws + off);  off += (size_t)NB * CAP * 8;   // 19.2 MB
    int* cnt      = (int*)(ws + off);   off += 8192;

    prep_w<<<128, 256, 0, stream>>>(w, wT, cnt);
    fused_mid<<<GEMM_BLOCKS + NBLK, 512, 0, stream>>>(x, wT, h, adj_row, adj_col,
                                                      adj_vals, cnt, metabuf);
    spmm_fused<<<NB, 512, 0, stream>>>(h, cnt, metabuf, b, out);
}